// Round 16
// baseline (318.663 us; speedup 1.0000x reference)
//
#include <hip/hip_runtime.h>
#include <hip/hip_bf16.h>
#include <math.h>

typedef __attribute__((ext_vector_type(8))) short bf16x8;
typedef __attribute__((ext_vector_type(16))) float f32x16;
typedef __attribute__((ext_vector_type(4))) unsigned int u32x4;
typedef __attribute__((ext_vector_type(2))) unsigned int u32x2;

constexpr int NB = 16, NQ = 4096, LF = 2048, C = 256;

__device__ __forceinline__ unsigned short bfbits(float x) {
    return __builtin_bit_cast(unsigned short, __float2bfloat16(x));
}
__device__ __forceinline__ unsigned pk2(float a, float b) {
    return (unsigned)bfbits(a) | ((unsigned)bfbits(b) << 16);
}
__device__ __forceinline__ float bflo(unsigned d) { return __builtin_bit_cast(float, d << 16); }
__device__ __forceinline__ float bfhi(unsigned d) { return __builtin_bit_cast(float, d & 0xffff0000u); }

// ---- prep: weights -> bf16 fragment-linear layout for 32x32x16 MFMA ----
// frag f = (nt*nks + ks)*64 + lane; elem e: w[nt*32 + (l&31)][ks*16 + (l>>5)*8 + e]
// offsets (ushort): w1c1=0, w1c2=16384, w2c1=32768, w2c2=49152, gw1=65536 (384 KiB total)
__global__ void prep_weights(const float* __restrict__ c1w1, const float* __restrict__ c2w1,
                             const float* __restrict__ c1w2, const float* __restrict__ c2w2,
                             const float* __restrict__ gw1, unsigned short* __restrict__ ws)
{
    int t = blockIdx.x * 256 + threadIdx.x;          // 0..24575
    const float* src; int K, nks, dstoff, f;
    if (t < 2048)      { src = c1w1; K = 256; nks = 16; dstoff = 0;      f = t; }
    else if (t < 4096) { src = c2w1; K = 256; nks = 16; dstoff = 16384;  f = t - 2048; }
    else if (t < 6144) { src = c1w2; K = 64;  nks = 4;  dstoff = 32768;  f = t - 4096; }
    else if (t < 8192) { src = c2w2; K = 64;  nks = 4;  dstoff = 49152;  f = t - 6144; }
    else               { src = gw1;  K = 512; nks = 32; dstoff = 65536;  f = t - 8192; }
    int l = f & 63, s = f >> 6;
    int nt = s / nks, ks = s % nks;
    int n  = nt * 32 + (l & 31);
    int k0 = ks * 16 + (l >> 5) * 8;
    unsigned short* d = ws + dstoff + (size_t)f * 8;
    const float* sp = src + (size_t)n * K + k0;
    #pragma unroll
    for (int e = 0; e < 8; ++e) d[e] = bfbits(sp[e]);
}

// ---- main: 32x32x16 MFMA, 32 rows (2 queries) per wave, AGPR peak 32 ----
__global__ __launch_bounds__(128, 4)
void semalign_v16(const float* __restrict__ feat,  const float* __restrict__ qbox,
                  const float* __restrict__ qfeat, const float* __restrict__ posf,
                  const float* __restrict__ c1b1,  const float* __restrict__ c1b2,
                  const float* __restrict__ c1g,   const float* __restrict__ c1be,
                  const float* __restrict__ c2b1,  const float* __restrict__ c2b2,
                  const float* __restrict__ c2g,   const float* __restrict__ c2be,
                  const float* __restrict__ gb1,   const float* __restrict__ gw2,
                  const float* __restrict__ gb2,
                  const unsigned short* __restrict__ wsb,
                  float* __restrict__ out)
{
    // per-wave 16 KiB: H [c=32][k=64] bf16 (4K) in head; pooled [c=32][n=256] bf16 (16K)
    // overwrites it after H is consumed into hf1/hf2 registers.
    __shared__ __align__(16) unsigned short sR[2][32][256];

    const int tid = threadIdx.x, l = tid & 63, wid = tid >> 6;
    const int c = l & 31, kh = l >> 5;
    const int rowb = blockIdx.x * 64 + wid * 32;
    const int b = c & 15;
    const int q = (rowb >> 4) + (c >> 4);
    const int swz = (c & 7) << 4;
    char* pbase = (char*)&sR[wid][0][0];

    const float* prow = posf  + ((size_t)b * NQ + q) * C;
    const float* qrow = qfeat + ((size_t)b * NQ + q) * C;
    float cx = qbox[((size_t)b * NQ + q) * 2 + 0];
    float w  = qbox[((size_t)b * NQ + q) * 2 + 1];
    float fs = fminf(fmaxf((cx - 0.5f * w) * (float)LF, 0.f), (float)(LF - 1));
    float fe = fminf(fmaxf((cx + 0.5f * w) * (float)LF, 0.f), (float)(LF - 1));
    const float* srow = feat + ((size_t)b * LF + (int)rintf(fs)) * C;
    const float* erow = feat + ((size_t)b * LF + (int)rintf(fe)) * C;

    // ---------- GEMM1 (contrasts sequential, 32 AGPR peak) -> H -> hf regs ----------
    bf16x8 hf1[4], hf2[4];
    #pragma unroll
    for (int j = 0; j < 2; ++j) {
        const unsigned short* w1b = wsb + (j ? 16384 : 0);
        const float* xr  = j ? erow : srow;
        const float* b1p = j ? c2b1 : c1b1;
        f32x16 a0 = {}, a1 = {};
        #pragma unroll
        for (int ks = 0; ks < 16; ++ks) {
            int k0 = ks * 16 + kh * 8;
            float4 x0 = *(const float4*)(xr + k0),  x1 = *(const float4*)(xr + k0 + 4);
            float4 p0 = *(const float4*)(prow + k0), p1 = *(const float4*)(prow + k0 + 4);
            u32x4 a;
            a[0] = pk2(x0.x * p0.x, x0.y * p0.y); a[1] = pk2(x0.z * p0.z, x0.w * p0.w);
            a[2] = pk2(x1.x * p1.x, x1.y * p1.y); a[3] = pk2(x1.z * p1.z, x1.w * p1.w);
            bf16x8 v = __builtin_bit_cast(bf16x8, a);
            bf16x8 w0 = *(const bf16x8*)(w1b + ((size_t)((0 * 16 + ks) * 64 + l)) * 8);
            bf16x8 w1f = *(const bf16x8*)(w1b + ((size_t)((1 * 16 + ks) * 64 + l)) * 8);
            a0 = __builtin_amdgcn_mfma_f32_32x32x16_bf16(w0, v, a0, 0, 0, 0);
            a1 = __builtin_amdgcn_mfma_f32_32x32x16_bf16(w1f, v, a1, 0, 0, 0);
        }
        #pragma unroll
        for (int nt = 0; nt < 2; ++nt) {
            f32x16 acc = nt ? a1 : a0;
            #pragma unroll
            for (int g = 0; g < 4; ++g) {
                int n0 = nt * 32 + 8 * g + 4 * kh;
                float4 bv = *(const float4*)(b1p + n0);
                u32x2 wv;
                wv[0] = pk2(fmaxf(acc[4 * g + 0] + bv.x, 0.f), fmaxf(acc[4 * g + 1] + bv.y, 0.f));
                wv[1] = pk2(fmaxf(acc[4 * g + 2] + bv.z, 0.f), fmaxf(acc[4 * g + 3] + bv.w, 0.f));
                *(u32x2*)(pbase + c * 128 + ((n0 * 2) ^ swz)) = wv;
            }
        }
        asm volatile("s_waitcnt lgkmcnt(0)" ::: "memory");
        #pragma unroll
        for (int ks2 = 0; ks2 < 4; ++ks2) {
            bf16x8 h = *(const bf16x8*)(pbase + c * 128 + (((ks2 * 16 + kh * 8) * 2) ^ swz));
            if (j == 0) hf1[ks2] = h; else hf2[ks2] = h;
        }
        asm volatile("s_waitcnt lgkmcnt(0)" ::: "memory");
    }

    // ---------- GEMM2 stats pass (per tile, 16 AGPR; u discarded) ----------
    float S1 = 0.f, Q21 = 0.f, S2 = 0.f, Q22 = 0.f;
    #pragma unroll
    for (int j = 0; j < 2; ++j) {
        const unsigned short* w2b = wsb + (j ? 49152 : 32768);
        const float* b2p = j ? c2b2 : c1b2;
        float S = 0.f, Q2 = 0.f;
        #pragma unroll
        for (int nt = 0; nt < 8; ++nt) {
            f32x16 u = {};
            #pragma unroll
            for (int ks2 = 0; ks2 < 4; ++ks2) {
                bf16x8 wf = *(const bf16x8*)(w2b + ((size_t)((nt * 4 + ks2) * 64 + l)) * 8);
                u = __builtin_amdgcn_mfma_f32_32x32x16_bf16(wf, j ? hf2[ks2] : hf1[ks2], u, 0, 0, 0);
            }
            #pragma unroll
            for (int g = 0; g < 4; ++g) {
                int n0 = nt * 32 + 8 * g + 4 * kh;
                float4 bv = *(const float4*)(b2p + n0);
                float b4[4] = { bv.x, bv.y, bv.z, bv.w };
                #pragma unroll
                for (int r = 0; r < 4; ++r) {
                    float v = u[4 * g + r] + b4[r];
                    S += v; Q2 += v * v;
                }
            }
        }
        if (j == 0) { S1 = S; Q21 = Q2; } else { S2 = S; Q22 = Q2; }
    }
    S1 += __shfl_xor(S1, 32); Q21 += __shfl_xor(Q21, 32);
    S2 += __shfl_xor(S2, 32); Q22 += __shfl_xor(Q22, 32);
    float mu1 = S1 * (1.f / 256.f), rs1 = rsqrtf(Q21 * (1.f / 256.f) - mu1 * mu1 + 1e-6f);
    float mu2 = S2 * (1.f / 256.f), rs2 = rsqrtf(Q22 * (1.f / 256.f) - mu2 * mu2 + 1e-6f);

    // ---------- GEMM2 recompute + LN + sigmoid + pooled, per tile ----------
    #pragma unroll
    for (int nt = 0; nt < 8; ++nt) {
        float tm1[16];
        {
            f32x16 u = {};
            #pragma unroll
            for (int ks2 = 0; ks2 < 4; ++ks2) {
                bf16x8 wf = *(const bf16x8*)(wsb + 32768 + ((size_t)((nt * 4 + ks2) * 64 + l)) * 8);
                u = __builtin_amdgcn_mfma_f32_32x32x16_bf16(wf, hf1[ks2], u, 0, 0, 0);
            }
            #pragma unroll
            for (int g = 0; g < 4; ++g) {
                int n0 = nt * 32 + 8 * g + 4 * kh;
                float4 bv = *(const float4*)(c1b2 + n0);
                float4 gv = *(const float4*)(c1g  + n0);
                float4 ev = *(const float4*)(c1be + n0);
                float4 xv = *(const float4*)(srow + n0);
                float b4[4] = { bv.x, bv.y, bv.z, bv.w };
                float g4[4] = { gv.x, gv.y, gv.z, gv.w };
                float e4[4] = { ev.x, ev.y, ev.z, ev.w };
                float x4[4] = { xv.x, xv.y, xv.z, xv.w };
                #pragma unroll
                for (int r = 0; r < 4; ++r) {
                    float ln = (u[4 * g + r] + b4[r] - mu1) * rs1 * g4[r] + e4[r];
                    float sg = 1.f / (1.f + __expf(-ln));
                    tm1[4 * g + r] = 0.5f * sg * x4[r];
                }
            }
        }
        {
            f32x16 u = {};
            #pragma unroll
            for (int ks2 = 0; ks2 < 4; ++ks2) {
                bf16x8 wf = *(const bf16x8*)(wsb + 49152 + ((size_t)((nt * 4 + ks2) * 64 + l)) * 8);
                u = __builtin_amdgcn_mfma_f32_32x32x16_bf16(wf, hf2[ks2], u, 0, 0, 0);
            }
            #pragma unroll
            for (int g = 0; g < 4; ++g) {
                int n0 = nt * 32 + 8 * g + 4 * kh;
                float4 bv = *(const float4*)(c2b2 + n0);
                float4 gv = *(const float4*)(c2g  + n0);
                float4 ev = *(const float4*)(c2be + n0);
                float4 xv = *(const float4*)(erow + n0);
                float b4[4] = { bv.x, bv.y, bv.z, bv.w };
                float g4[4] = { gv.x, gv.y, gv.z, gv.w };
                float e4[4] = { ev.x, ev.y, ev.z, ev.w };
                float x4[4] = { xv.x, xv.y, xv.z, xv.w };
                float pm[4];
                #pragma unroll
                for (int r = 0; r < 4; ++r) {
                    float ln = (u[4 * g + r] + b4[r] - mu2) * rs2 * g4[r] + e4[r];
                    float sg = 1.f / (1.f + __expf(-ln));
                    pm[r] = tm1[4 * g + r] + 0.5f * sg * x4[r];
                }
                u32x2 wv;
                wv[0] = pk2(pm[0], pm[1]); wv[1] = pk2(pm[2], pm[3]);
                *(u32x2*)(pbase + c * 512 + ((nt * 64 + 16 * g + 8 * kh) ^ swz)) = wv;
            }
        }
    }
    asm volatile("s_waitcnt lgkmcnt(0)" ::: "memory");

    // ---------- gate GEMM: 4 passes x 2 tiles (32 AGPR), x-frag rebuilt per pass ----------
    float t0 = 0.f, t1 = 0.f;
    const unsigned short* gwb = wsb + 65536;
    #pragma clang loop unroll(disable)
    for (int p = 0; p < 4; ++p) {
        f32x16 ga0 = {}, ga1 = {};
        #pragma clang loop unroll(disable)
        for (int kk = 0; kk < 32; ++kk) {
            bf16x8 xk;
            if (kk < 16) {
                xk = *(const bf16x8*)(pbase + c * 512 + (((kk * 16 + kh * 8) * 2) ^ swz));
            } else {
                int k0 = (kk - 16) * 16 + kh * 8;
                float4 q0 = *(const float4*)(qrow + k0), q1 = *(const float4*)(qrow + k0 + 4);
                u32x4 a;
                a[0] = pk2(q0.x, q0.y); a[1] = pk2(q0.z, q0.w);
                a[2] = pk2(q1.x, q1.y); a[3] = pk2(q1.z, q1.w);
                xk = __builtin_bit_cast(bf16x8, a);
            }
            bf16x8 w0 = *(const bf16x8*)(gwb + ((size_t)(((2 * p + 0) * 32 + kk) * 64 + l)) * 8);
            bf16x8 w1f = *(const bf16x8*)(gwb + ((size_t)(((2 * p + 1) * 32 + kk) * 64 + l)) * 8);
            ga0 = __builtin_amdgcn_mfma_f32_32x32x16_bf16(w0, xk, ga0, 0, 0, 0);
            ga1 = __builtin_amdgcn_mfma_f32_32x32x16_bf16(w1f, xk, ga1, 0, 0, 0);
        }
        #pragma unroll
        for (int t2 = 0; t2 < 2; ++t2) {
            f32x16 ga = t2 ? ga1 : ga0;
            #pragma unroll
            for (int g = 0; g < 4; ++g) {
                int n0 = (2 * p + t2) * 32 + 8 * g + 4 * kh;
                float4 gbv = *(const float4*)(gb1 + n0);
                float4 w0v = *(const float4*)(gw2 + n0);
                float4 w1v = *(const float4*)(gw2 + 256 + n0);
                float gb4[4] = { gbv.x, gbv.y, gbv.z, gbv.w };
                float w04[4] = { w0v.x, w0v.y, w0v.z, w0v.w };
                float w14[4] = { w1v.x, w1v.y, w1v.z, w1v.w };
                #pragma unroll
                for (int r = 0; r < 4; ++r) {
                    float hv = fmaxf(ga[4 * g + r] + gb4[r], 0.f);
                    t0 += hv * w04[r]; t1 += hv * w14[r];
                }
            }
        }
    }
    t0 += __shfl_xor(t0, 32); t1 += __shfl_xor(t1, 32);
    float g0 = 1.f / (1.f + __expf((t1 + gb2[1]) - (t0 + gb2[0])));
    float g1 = 1.f - g0;

    // ---------- epilogue: lane covers 128 channels of its row ----------
    float* orow = out + (size_t)(rowb + c) * C;
    #pragma unroll
    for (int jj = 0; jj < 16; ++jj) {
        int ch = kh * 128 + jj * 8;
        bf16x8 pf = *(const bf16x8*)(pbase + c * 512 + ((ch * 2) ^ swz));
        u32x4 pu = __builtin_bit_cast(u32x4, pf);
        float4 q0 = *(const float4*)(qrow + ch), q1 = *(const float4*)(qrow + ch + 4);
        float4 o0, o1;
        o0.x = bflo(pu[0]) * g0 + q0.x * g1;
        o0.y = bfhi(pu[0]) * g0 + q0.y * g1;
        o0.z = bflo(pu[1]) * g0 + q0.z * g1;
        o0.w = bfhi(pu[1]) * g0 + q0.w * g1;
        o1.x = bflo(pu[2]) * g0 + q1.x * g1;
        o1.y = bfhi(pu[2]) * g0 + q1.y * g1;
        o1.z = bflo(pu[3]) * g0 + q1.z * g1;
        o1.w = bfhi(pu[3]) * g0 + q1.w * g1;
        *(float4*)(orow + ch)     = o0;
        *(float4*)(orow + ch + 4) = o1;
    }
}

extern "C" void kernel_launch(void* const* d_in, const int* in_sizes, int n_in,
                              void* d_out, int out_size, void* d_ws, size_t ws_size,
                              hipStream_t stream) {
    const float* feat  = (const float*)d_in[0];
    const float* qbox  = (const float*)d_in[1];
    const float* qfeat = (const float*)d_in[2];
    const float* posf  = (const float*)d_in[3];
    const float* c1w1  = (const float*)d_in[4];
    const float* c1b1  = (const float*)d_in[5];
    const float* c1w2  = (const float*)d_in[6];
    const float* c1b2  = (const float*)d_in[7];
    const float* c1g   = (const float*)d_in[8];
    const float* c1be  = (const float*)d_in[9];
    const float* c2w1  = (const float*)d_in[10];
    const float* c2b1  = (const float*)d_in[11];
    const float* c2w2  = (const float*)d_in[12];
    const float* c2b2  = (const float*)d_in[13];
    const float* c2g   = (const float*)d_in[14];
    const float* c2be  = (const float*)d_in[15];
    const float* gw1   = (const float*)d_in[16];
    const float* gb1   = (const float*)d_in[17];
    const float* gw2   = (const float*)d_in[18];
    const float* gb2   = (const float*)d_in[19];
    float* out = (float*)d_out;
    unsigned short* wsb = (unsigned short*)d_ws;   // 393216 B used

    prep_weights<<<96, 256, 0, stream>>>(c1w1, c2w1, c1w2, c2w2, gw1, wsb);

    dim3 grid((NB * NQ) / 64), block(128);         // 1024 blocks, 2 waves, 32 rows/wave
    semalign_v16<<<grid, block, 0, stream>>>(
        feat, qbox, qfeat, posf,
        c1b1, c1b2, c1g, c1be,
        c2b1, c2b2, c2g, c2be,
        gb1, gw2, gb2, wsb, out);
}

// Round 17
// 162.817 us; speedup vs baseline: 1.9572x; 1.9572x over previous
//
#include <hip/hip_runtime.h>
#include <hip/hip_bf16.h>
#include <math.h>

typedef __attribute__((ext_vector_type(8))) short bf16x8;
typedef __attribute__((ext_vector_type(4))) float f32x4;
typedef __attribute__((ext_vector_type(2))) __fp16 f16x2;
typedef __attribute__((ext_vector_type(4))) unsigned int u32x4;
typedef __attribute__((ext_vector_type(2))) unsigned int u32x2;

constexpr int NB = 16, NQ = 4096, LF = 2048, C = 256;

__device__ __forceinline__ unsigned short bfbits(float x) {
    return __builtin_bit_cast(unsigned short, __float2bfloat16(x));
}
__device__ __forceinline__ unsigned pk2(float a, float b) {
    return (unsigned)bfbits(a) | ((unsigned)bfbits(b) << 16);
}
__device__ __forceinline__ float bflo(unsigned d) { return __builtin_bit_cast(float, d << 16); }
__device__ __forceinline__ float bfhi(unsigned d) { return __builtin_bit_cast(float, d & 0xffff0000u); }
__device__ __forceinline__ unsigned pkh(float a, float b) {
    f16x2 h = __builtin_amdgcn_cvt_pkrtz(a, b);
    return __builtin_bit_cast(unsigned, h);
}
__device__ __forceinline__ float hlo(unsigned u) {
    f16x2 h = __builtin_bit_cast(f16x2, u); return (float)h[0];
}
__device__ __forceinline__ float hhi(unsigned u) {
    f16x2 h = __builtin_bit_cast(f16x2, u); return (float)h[1];
}

// ---- prep: weights -> bf16 fragment-linear layout in ws (R4-verified) ----
__global__ void prep_weights(const float* __restrict__ c1w1, const float* __restrict__ c2w1,
                             const float* __restrict__ c1w2, const float* __restrict__ c2w2,
                             const float* __restrict__ gw1, unsigned short* __restrict__ ws)
{
    int t = blockIdx.x * 256 + threadIdx.x;          // 0..24575
    const float* src; int K, nks, dstoff, f;
    if (t < 2048)      { src = c1w1; K = 256; nks = 8;  dstoff = 0;      f = t; }
    else if (t < 4096) { src = c2w1; K = 256; nks = 8;  dstoff = 16384;  f = t - 2048; }
    else if (t < 6144) { src = c1w2; K = 64;  nks = 2;  dstoff = 32768;  f = t - 4096; }
    else if (t < 8192) { src = c2w2; K = 64;  nks = 2;  dstoff = 49152;  f = t - 6144; }
    else               { src = gw1;  K = 512; nks = 16; dstoff = 65536;  f = t - 8192; }
    int l = f & 63, s = f >> 6;
    int nt = s / nks, ks = s % nks;
    int n  = nt * 16 + (l & 15);
    int k0 = ks * 32 + (l >> 4) * 8;
    unsigned short* d = ws + dstoff + (size_t)f * 8;
    const float* sp = src + (size_t)n * K + k0;
    #pragma unroll
    for (int e = 0; e < 8; ++e) d[e] = bfbits(sp[e]);
}

// ---- main: R14 + GEMM1 activation frags computed inline (spill removal) ----
__global__ __launch_bounds__(256, 4)
void semalign_v17(const float* __restrict__ feat,  const float* __restrict__ qbox,
                  const float* __restrict__ qfeat, const float* __restrict__ posf,
                  const float* __restrict__ c1b1,  const float* __restrict__ c1b2,
                  const float* __restrict__ c1g,   const float* __restrict__ c1be,
                  const float* __restrict__ c2b1,  const float* __restrict__ c2b2,
                  const float* __restrict__ c2g,   const float* __restrict__ c2be,
                  const float* __restrict__ gb1,   const float* __restrict__ gw2,
                  const float* __restrict__ gb2,
                  const unsigned short* __restrict__ wsb,
                  float* __restrict__ out)
{
    // per-wave 8 KiB region: H0 at +0 (2K), H1 at +2048 (2K), u-stash at +4096 (4K);
    // pooled overwrites the whole region at the end (all prior contents consumed).
    __shared__ __align__(16) unsigned short sP[4][16][256];

    const int tid = threadIdx.x, l = tid & 63, wid = tid >> 6;
    const int lr = l & 15, lg = l >> 4;
    const int rowb = blockIdx.x * 64 + wid * 16;
    const int q = rowb >> 4;
    const int b = lr;
    const int swz = (lr & 7) << 4;

    const float* prow = posf  + ((size_t)b * NQ + q) * C;
    const float* qrow = qfeat + ((size_t)b * NQ + q) * C;
    float cx = qbox[((size_t)b * NQ + q) * 2 + 0];
    float w  = qbox[((size_t)b * NQ + q) * 2 + 1];
    float fs = fminf(fmaxf((cx - 0.5f * w) * (float)LF, 0.f), (float)(LF - 1));
    float fe = fminf(fmaxf((cx + 0.5f * w) * (float)LF, 0.f), (float)(LF - 1));
    const float* srow = feat + ((size_t)b * LF + (int)rintf(fs)) * C;
    const float* erow = feat + ((size_t)b * LF + (int)rintf(fe)) * C;

    // ---------- GEMM1: activation frags computed inline per ks (low VGPR) ----------
    char* pb = (char*)&sP[wid][0][0];
    {
        f32x4 a1[4] = {}, a2[4] = {};
        #pragma unroll
        for (int ks = 0; ks < 8; ++ks) {
            int k0 = ks * 32 + lg * 8;
            float4 s0 = *(const float4*)(srow + k0), s1 = *(const float4*)(srow + k0 + 4);
            float4 e0 = *(const float4*)(erow + k0), e1 = *(const float4*)(erow + k0 + 4);
            float4 p0 = *(const float4*)(prow + k0), p1 = *(const float4*)(prow + k0 + 4);
            u32x4 av, cv;
            av[0] = pk2(s0.x * p0.x, s0.y * p0.y); av[1] = pk2(s0.z * p0.z, s0.w * p0.w);
            av[2] = pk2(s1.x * p1.x, s1.y * p1.y); av[3] = pk2(s1.z * p1.z, s1.w * p1.w);
            cv[0] = pk2(e0.x * p0.x, e0.y * p0.y); cv[1] = pk2(e0.z * p0.z, e0.w * p0.w);
            cv[2] = pk2(e1.x * p1.x, e1.y * p1.y); cv[3] = pk2(e1.z * p1.z, e1.w * p1.w);
            bf16x8 v1 = __builtin_bit_cast(bf16x8, av);
            bf16x8 v2 = __builtin_bit_cast(bf16x8, cv);
            #pragma unroll
            for (int nt = 0; nt < 4; ++nt) {
                bf16x8 wA = *(const bf16x8*)(wsb + ((size_t)((nt * 8 + ks) * 64 + l)) * 8);
                bf16x8 wB = *(const bf16x8*)(wsb + 16384 + ((size_t)((nt * 8 + ks) * 64 + l)) * 8);
                a1[nt] = __builtin_amdgcn_mfma_f32_16x16x32_bf16(wA, v1, a1[nt], 0, 0, 0);
                a2[nt] = __builtin_amdgcn_mfma_f32_16x16x32_bf16(wB, v2, a2[nt], 0, 0, 0);
            }
        }
        #pragma unroll
        for (int nt = 0; nt < 4; ++nt) {
            float4 b1v = *(const float4*)(c1b1 + nt * 16 + lg * 4);
            float4 b2v = *(const float4*)(c2b1 + nt * 16 + lg * 4);
            u32x2 wv;
            wv[0] = pk2(fmaxf(a1[nt][0] + b1v.x, 0.f), fmaxf(a1[nt][1] + b1v.y, 0.f));
            wv[1] = pk2(fmaxf(a1[nt][2] + b1v.z, 0.f), fmaxf(a1[nt][3] + b1v.w, 0.f));
            *(u32x2*)(pb + lr * 128 + ((nt * 32 + lg * 8) ^ swz)) = wv;
            wv[0] = pk2(fmaxf(a2[nt][0] + b2v.x, 0.f), fmaxf(a2[nt][1] + b2v.y, 0.f));
            wv[1] = pk2(fmaxf(a2[nt][2] + b2v.z, 0.f), fmaxf(a2[nt][3] + b2v.w, 0.f));
            *(u32x2*)(pb + 2048 + lr * 128 + ((nt * 32 + lg * 8) ^ swz)) = wv;
        }
    }

    // ---------- GEMM2 + LN + sigmoid + pooled, halved accumulator (R13-verified) ----------
    f16x2 Ph[16][2];
    #pragma unroll
    for (int j = 0; j < 2; ++j) {
        char* hb = pb + j * 2048;
        asm volatile("s_waitcnt lgkmcnt(0)" ::: "memory");
        bf16x8 hf0 = *(const bf16x8*)(hb + lr * 128 + ((0 + lg * 16) ^ swz));
        bf16x8 hf1 = *(const bf16x8*)(hb + lr * 128 + ((64 + lg * 16) ^ swz));
        const unsigned short* w2b = wsb + (j ? 49152 : 32768);
        const float* b2p = j ? c2b2 : c1b2;
        const float* gp  = j ? c2g  : c1g;
        const float* bep = j ? c2be : c1be;
        const float* xrow = j ? erow : srow;
        float S = 0.f, Q2 = 0.f;

        // half 0: nt 0..7 -> bias+stats -> fp16 stash in LDS (pb+4096)
        {
            f32x4 u8[8] = {};
            #pragma unroll
            for (int nt = 0; nt < 8; ++nt) {
                bf16x8 wA = *(const bf16x8*)(w2b + ((size_t)((nt * 2 + 0) * 64 + l)) * 8);
                bf16x8 wB = *(const bf16x8*)(w2b + ((size_t)((nt * 2 + 1) * 64 + l)) * 8);
                u8[nt] = __builtin_amdgcn_mfma_f32_16x16x32_bf16(wA, hf0, u8[nt], 0, 0, 0);
                u8[nt] = __builtin_amdgcn_mfma_f32_16x16x32_bf16(wB, hf1, u8[nt], 0, 0, 0);
            }
            #pragma unroll
            for (int nt = 0; nt < 8; ++nt) {
                float4 bv = *(const float4*)(b2p + nt * 16 + lg * 4);
                u8[nt][0] += bv.x; u8[nt][1] += bv.y; u8[nt][2] += bv.z; u8[nt][3] += bv.w;
                S  += u8[nt][0] + u8[nt][1] + u8[nt][2] + u8[nt][3];
                Q2 += u8[nt][0] * u8[nt][0] + u8[nt][1] * u8[nt][1]
                    + u8[nt][2] * u8[nt][2] + u8[nt][3] * u8[nt][3];
                u32x2 wv;
                wv[0] = pkh(u8[nt][0], u8[nt][1]);
                wv[1] = pkh(u8[nt][2], u8[nt][3]);
                *(u32x2*)(pb + 4096 + nt * 512 + l * 8) = wv;
            }
        }
        // half 1: nt 8..15 kept in AGPRs
        f32x4 u8b[8] = {};
        #pragma unroll
        for (int nt = 0; nt < 8; ++nt) {
            bf16x8 wA = *(const bf16x8*)(w2b + ((size_t)(((nt + 8) * 2 + 0) * 64 + l)) * 8);
            bf16x8 wB = *(const bf16x8*)(w2b + ((size_t)(((nt + 8) * 2 + 1) * 64 + l)) * 8);
            u8b[nt] = __builtin_amdgcn_mfma_f32_16x16x32_bf16(wA, hf0, u8b[nt], 0, 0, 0);
            u8b[nt] = __builtin_amdgcn_mfma_f32_16x16x32_bf16(wB, hf1, u8b[nt], 0, 0, 0);
        }
        #pragma unroll
        for (int nt = 0; nt < 8; ++nt) {
            float4 bv = *(const float4*)(b2p + (nt + 8) * 16 + lg * 4);
            u8b[nt][0] += bv.x; u8b[nt][1] += bv.y; u8b[nt][2] += bv.z; u8b[nt][3] += bv.w;
            S  += u8b[nt][0] + u8b[nt][1] + u8b[nt][2] + u8b[nt][3];
            Q2 += u8b[nt][0] * u8b[nt][0] + u8b[nt][1] * u8b[nt][1]
                + u8b[nt][2] * u8b[nt][2] + u8b[nt][3] * u8b[nt][3];
        }
        S  += __shfl_xor(S, 16);  S  += __shfl_xor(S, 32);
        Q2 += __shfl_xor(Q2, 16); Q2 += __shfl_xor(Q2, 32);
        float mu  = S * (1.f / 256.f);
        float rsg = rsqrtf(Q2 * (1.f / 256.f) - mu * mu + 1e-6f);

        // read back stash BEFORE any pooled write (j=1 writes overwrite stash region)
        u32x2 st[8];
        asm volatile("s_waitcnt lgkmcnt(0)" ::: "memory");
        #pragma unroll
        for (int nt = 0; nt < 8; ++nt)
            st[nt] = *(const u32x2*)(pb + 4096 + nt * 512 + l * 8);
        asm volatile("s_waitcnt lgkmcnt(0)" ::: "memory");

        #pragma unroll
        for (int nt = 0; nt < 16; ++nt) {
            float u4[4];
            if (nt < 8) {
                u4[0] = hlo(st[nt][0]); u4[1] = hhi(st[nt][0]);
                u4[2] = hlo(st[nt][1]); u4[3] = hhi(st[nt][1]);
            } else {
                u4[0] = u8b[nt - 8][0]; u4[1] = u8b[nt - 8][1];
                u4[2] = u8b[nt - 8][2]; u4[3] = u8b[nt - 8][3];
            }
            float4 gv  = *(const float4*)(gp  + nt * 16 + lg * 4);
            float4 bev = *(const float4*)(bep + nt * 16 + lg * 4);
            float4 xv  = *(const float4*)(xrow + nt * 16 + lg * 4);
            float g4[4] = { gv.x, gv.y, gv.z, gv.w };
            float e4[4] = { bev.x, bev.y, bev.z, bev.w };
            float x4[4] = { xv.x, xv.y, xv.z, xv.w };
            float tm[4];
            #pragma unroll
            for (int r = 0; r < 4; ++r) {
                float ln = (u4[r] - mu) * rsg * g4[r] + e4[r];
                float sg = 1.f / (1.f + __expf(-ln));
                tm[r] = 0.5f * sg * x4[r];
            }
            if (j == 0) {
                Ph[nt][0] = __builtin_amdgcn_cvt_pkrtz(tm[0], tm[1]);
                Ph[nt][1] = __builtin_amdgcn_cvt_pkrtz(tm[2], tm[3]);
            } else {
                float p0 = (float)Ph[nt][0][0] + tm[0];
                float p1 = (float)Ph[nt][0][1] + tm[1];
                float p2 = (float)Ph[nt][1][0] + tm[2];
                float p3 = (float)Ph[nt][1][1] + tm[3];
                u32x2 wv;
                wv[0] = pk2(p0, p1); wv[1] = pk2(p2, p3);
                *(u32x2*)(pb + lr * 512 + ((nt * 32 + lg * 8) ^ swz)) = wv;
            }
        }
    }
    asm volatile("s_waitcnt lgkmcnt(0)" ::: "memory");

    // ---------- gate GEMM, transposed loop: ga[16] in AGPRs, 1 live x-frag ----------
    f32x4 ga[16] = {};
    const unsigned short* gwb = wsb + 65536;
    #pragma clang loop unroll(disable)
    for (int kk = 0; kk < 16; ++kk) {
        bf16x8 xk;
        if (kk < 8) {
            xk = *(const bf16x8*)(pb + lr * 512 + ((kk * 64 + lg * 16) ^ swz));
        } else {
            int k0 = (kk - 8) * 32 + lg * 8;
            float4 q0 = *(const float4*)(qrow + k0), q1 = *(const float4*)(qrow + k0 + 4);
            u32x4 a;
            a[0] = pk2(q0.x, q0.y); a[1] = pk2(q0.z, q0.w);
            a[2] = pk2(q1.x, q1.y); a[3] = pk2(q1.z, q1.w);
            xk = __builtin_bit_cast(bf16x8, a);
        }
        #pragma unroll
        for (int nt = 0; nt < 16; ++nt) {
            bf16x8 wf = *(const bf16x8*)(gwb + ((size_t)((nt * 16 + kk) * 64 + l)) * 8);
            ga[nt] = __builtin_amdgcn_mfma_f32_16x16x32_bf16(wf, xk, ga[nt], 0, 0, 0);
        }
    }

    // ---------- logits + softmax(2) ----------
    float t0 = 0.f, t1 = 0.f;
    #pragma unroll
    for (int nt = 0; nt < 16; ++nt) {
        float4 gbv = *(const float4*)(gb1 + nt * 16 + lg * 4);
        float4 w0v = *(const float4*)(gw2 + nt * 16 + lg * 4);
        float4 w1v = *(const float4*)(gw2 + 256 + nt * 16 + lg * 4);
        float gb4[4] = { gbv.x, gbv.y, gbv.z, gbv.w };
        float w04[4] = { w0v.x, w0v.y, w0v.z, w0v.w };
        float w14[4] = { w1v.x, w1v.y, w1v.z, w1v.w };
        #pragma unroll
        for (int r = 0; r < 4; ++r) {
            float hv = fmaxf(ga[nt][r] + gb4[r], 0.f);
            t0 += hv * w04[r]; t1 += hv * w14[r];
        }
    }
    t0 += __shfl_xor(t0, 16); t0 += __shfl_xor(t0, 32);
    t1 += __shfl_xor(t1, 16); t1 += __shfl_xor(t1, 32);
    float g0 = 1.f / (1.f + __expf((t1 + gb2[1]) - (t0 + gb2[0])));
    float g1 = 1.f - g0;

    // ---------- epilogue: pooled re-read from LDS, qf from global (f32) ----------
    float* orow = out + (size_t)(rowb + lr) * C;
    #pragma unroll
    for (int ks = 0; ks < 8; ++ks) {
        bf16x8 pf = *(const bf16x8*)(pb + lr * 512 + ((ks * 64 + lg * 16) ^ swz));
        u32x4 pu = __builtin_bit_cast(u32x4, pf);
        int k0 = ks * 32 + lg * 8;
        float4 q0 = *(const float4*)(qrow + k0), q1 = *(const float4*)(qrow + k0 + 4);
        float4 o0, o1;
        o0.x = bflo(pu[0]) * g0 + q0.x * g1;
        o0.y = bfhi(pu[0]) * g0 + q0.y * g1;
        o0.z = bflo(pu[1]) * g0 + q0.z * g1;
        o0.w = bfhi(pu[1]) * g0 + q0.w * g1;
        o1.x = bflo(pu[2]) * g0 + q1.x * g1;
        o1.y = bfhi(pu[2]) * g0 + q1.y * g1;
        o1.z = bflo(pu[3]) * g0 + q1.z * g1;
        o1.w = bfhi(pu[3]) * g0 + q1.w * g1;
        *(float4*)(orow + ks * 32 + lg * 8)     = o0;
        *(float4*)(orow + ks * 32 + lg * 8 + 4) = o1;
    }
}

extern "C" void kernel_launch(void* const* d_in, const int* in_sizes, int n_in,
                              void* d_out, int out_size, void* d_ws, size_t ws_size,
                              hipStream_t stream) {
    const float* feat  = (const float*)d_in[0];
    const float* qbox  = (const float*)d_in[1];
    const float* qfeat = (const float*)d_in[2];
    const float* posf  = (const float*)d_in[3];
    const float* c1w1  = (const float*)d_in[4];
    const float* c1b1  = (const float*)d_in[5];
    const float* c1w2  = (const float*)d_in[6];
    const float* c1b2  = (const float*)d_in[7];
    const float* c1g   = (const float*)d_in[8];
    const float* c1be  = (const float*)d_in[9];
    const float* c2w1  = (const float*)d_in[10];
    const float* c2b1  = (const float*)d_in[11];
    const float* c2w2  = (const float*)d_in[12];
    const float* c2b2  = (const float*)d_in[13];
    const float* c2g   = (const float*)d_in[14];
    const float* c2be  = (const float*)d_in[15];
    const float* gw1   = (const float*)d_in[16];
    const float* gb1   = (const float*)d_in[17];
    const float* gw2   = (const float*)d_in[18];
    const float* gb2   = (const float*)d_in[19];
    float* out = (float*)d_out;
    unsigned short* wsb = (unsigned short*)d_ws;   // 393216 B used

    prep_weights<<<96, 256, 0, stream>>>(c1w1, c2w1, c1w2, c2w2, gw1, wsb);

    dim3 grid((NB * NQ) / 64), block(256);         // 1024 blocks, 4 waves, 16 rows/wave
    semalign_v17<<<grid, block, 0, stream>>>(
        feat, qbox, qfeat, posf,
        c1b1, c1b2, c1g, c1be,
        c2b1, c2b2, c2g, c2be,
        gb1, gw2, gb2, wsb, out);
}